// Round 6
// baseline (260.347 us; speedup 1.0000x reference)
//
#include <hip/hip_runtime.h>
#include <hip/hip_bf16.h>
#include <cstdint>

#define NPTS (2048 * 192)          // 393216 points
#define TBL  (1u << 19)            // hash table size per level
#define TMASK (TBL - 1u)
#define PBLOCKS (NPTS / 256)       // 1536 blocks per level
#define ENC_BLOCKS (PBLOCKS * 16)  // 24576
#define PREP_BLOCKS 6              // 24 frags * 64 lanes / 256
#define PE_BLOCKS PBLOCKS          // 1536 dir-PE precompute blocks
#define MLP_WORK_BLOCKS 3072       // real work: 3072 blocks * 4 waves * 2 groups * 16 pts
#define MLP_BLOCKS 6144            // DIAGNOSTIC x2: second half redoes identical work
#define P2 2654435761u
#define P3 805459861u

// geomspace(16, 2048, 16).astype(int)
__constant__ float LVLS[16] = {16.f, 22.f, 30.f, 42.f, 58.f, 80.f, 111.f, 153.f,
                               212.f, 294.f, 406.f, 561.f, 776.f, 1072.f, 1482.f, 2048.f};

__device__ __forceinline__ uint32_t f2bf(float f) {
    uint32_t u = __float_as_uint(f);
    return (u + 0x7FFFu + ((u >> 16) & 1u)) >> 16;   // RNE bf16 (weights/feats)
}
__device__ __forceinline__ uint32_t pack2(float a, float b) {
    return f2bf(a) | (f2bf(b) << 16);
}
// 1-instruction truncating bf16 pack: [a_hi16 | b_hi16 << 16] via v_perm_b32.
__device__ __forceinline__ uint32_t pack2t(float a, float b) {
    return __builtin_amdgcn_perm(__float_as_uint(b), __float_as_uint(a),
                                 0x07060302u);
}

#if __has_builtin(__builtin_amdgcn_sinf)
#define SIN_REV(x) __builtin_amdgcn_sinf(x)   // sin(2*pi*x)
#else
#define SIN_REV(x) __sinf(6.28318530717958647f * (x))
#endif

typedef __attribute__((ext_vector_type(8))) short bf16x8;   // MFMA A/B frag
typedef __attribute__((ext_vector_type(4))) float f32x4;    // MFMA C/D frag

#define MFMA_BF16 __builtin_amdgcn_mfma_f32_16x16x32_bf16

// av-vector row value for rows 16..63. ONE transcendental per row:
// cos(x) = sin(x + 0.25 rev). Evaluated once per point in the k_encode tail.
__device__ __forceinline__ float pe_val(int r, float rx, float ry, float rz)
{
    int t = r - 19;
    int d = t >> 3;
    int s = t & 7;
    float comp = (d == 0) ? rx : ((d == 1) ? ry : rz);
    float a = ldexpf(comp, s & 3) + ((s >= 4) ? 0.25f : 0.0f);
    float v = SIN_REV(a);
    if (r == 16) v = rx;
    if (r == 17) v = ry;
    if (r == 18) v = rz;
    if (r == 43) v = 1.0f;
    if (r > 43)  v = 0.0f;
    return v;
}

// ---------------------------------------------------------------------------
// Kernel 1: hash-grid encode + (tail) weight prepack + (tail) dir-PE planes.
// UNCHANGED (best measured ~119.5us avg; near TCC request-rate floor with
// ~94% L2 hit from XCD-affine level mapping).
// ---------------------------------------------------------------------------
__global__ __launch_bounds__(256) void k_encode(const float* __restrict__ x,
                                                const float* __restrict__ tables,
                                                uint32_t* __restrict__ feats,
                                                const float* __restrict__ dW1,
                                                const float* __restrict__ dW2,
                                                const float* __restrict__ cW1,
                                                const float* __restrict__ cb1,
                                                const float* __restrict__ cW2,
                                                const float* __restrict__ cW3,
                                                uint4* __restrict__ wfrags,
                                                const float* __restrict__ rdir,
                                                uint32_t* __restrict__ dirs)
{
    if (blockIdx.x >= ENC_BLOCKS + PREP_BLOCKS) {
        // ---- dir positional-encoding precompute (1536 tail blocks) ----
        int p = (blockIdx.x - ENC_BLOCKS - PREP_BLOCKS) * 256 + threadIdx.x;
        size_t p3 = (size_t)p * 3;
        float rx = rdir[p3 + 0], ry = rdir[p3 + 1], rz = rdir[p3 + 2];
#pragma unroll
        for (int i = 0; i < 14; ++i)
            dirs[(size_t)i * NPTS + p] =
                pack2t(pe_val(16 + 2 * i, rx, ry, rz),
                       pe_val(17 + 2 * i, rx, ry, rz));
        return;
    }
    if (blockIdx.x >= ENC_BLOCKS) {
        // ---- weight prepack (6 tail blocks; consumed by k_mlp) ----
        int t = (blockIdx.x - ENC_BLOCKS) * 256 + threadIdx.x;
        if (t >= 24 * 64) return;
        int frag = t >> 6, lane = t & 63;
        const float* W; const float* bfold = nullptr;
        int OUT, Kact, Mact, k0, m0;
        if (frag < 4)       { W = dW1; OUT = 64; Kact = 32; Mact = 64; k0 = 0;               m0 = frag * 16; }
        else if (frag < 6)  { W = dW2; OUT = 16; Kact = 64; Mact = 16; k0 = (frag - 4) * 32; m0 = 0; }
        else if (frag < 14) { int i = frag - 6;  W = cW1; OUT = 64; Kact = 43; Mact = 64;
                              k0 = (i & 1) * 32; m0 = (i >> 1) * 16; bfold = cb1; }
        else if (frag < 22) { int i = frag - 14; W = cW2; OUT = 64; Kact = 64; Mact = 64;
                              k0 = (i & 1) * 32; m0 = (i >> 1) * 16; }
        else                { W = cW3; OUT = 3;  Kact = 64; Mact = 3;  k0 = (frag - 22) * 32; m0 = 0; }
        int m  = m0 + (lane & 15);
        int kq = k0 + ((lane >> 4) << 3);
        uint32_t d[4];
#pragma unroll
        for (int j = 0; j < 4; ++j) {
            float a0 = 0.f, a1 = 0.f;
            int ka = kq + 2 * j, kb = ka + 1;
            if (m < Mact) {
                a0 = (ka < Kact) ? W[(size_t)ka * OUT + m]
                                 : ((bfold && ka == Kact) ? bfold[m] : 0.f);
                a1 = (kb < Kact) ? W[(size_t)kb * OUT + m]
                                 : ((bfold && kb == Kact) ? bfold[m] : 0.f);
            }
            d[j] = f2bf(a0) | (f2bf(a1) << 16);
        }
        wfrags[t] = make_uint4(d[0], d[1], d[2], d[3]);
        return;
    }

    // ---- XCD-affine decode of (level, point-block) ----
    int xs   = blockIdx.x & 7;          // XCD slot
    int i    = blockIdx.x >> 3;         // 0..3071
    int half = i / PBLOCKS;             // 0: levels 0-7, 1: levels 8-15
    int pb   = i - half * PBLOCKS;      // point-block 0..1535
    int lvl  = xs + (half << 3);
    int p    = pb * 256 + threadIdx.x;

    size_t p3 = (size_t)p * 3;
    float x0 = x[p3 + 0] + 0.5f;
    float x1 = x[p3 + 1] + 0.5f;
    float x2 = x[p3 + 2] + 0.5f;
    size_t oidx = (size_t)lvl * NPTS + p;

    bool m = (x0 > 0.f) && (x0 < 1.f) && (x1 > 0.f) && (x1 < 1.f) &&
             (x2 > 0.f) && (x2 < 1.f);
    if (!m) { feats[oidx] = 0u; return; }   // masked: features never used

    float s  = LVLS[lvl];
    float px = x0 * s, py = x1 * s, pz = x2 * s;
    float flx = floorf(px), fly = floorf(py), flz = floorf(pz);
    float frx = px - flx,   fry = py - fly,   frz = pz - flz;
    int ix = (int)flx, iy = (int)fly, iz = (int)flz;
    uint32_t ux = (uint32_t)ix, uy = (uint32_t)iy, uz = (uint32_t)iz;

    uint32_t base[4];
    base[0] = (uy * P2) ^ (uz * P3);
    base[1] = ((uy + 1u) * P2) ^ (uz * P3);
    base[2] = (uy * P2) ^ ((uz + 1u) * P3);
    base[3] = ((uy + 1u) * P2) ^ ((uz + 1u) * P3);

    const float2* tb = (const float2*)tables + (size_t)lvl * TBL;

    float2 v[8];
    if ((ix & 1) == 0) {
        // even ix: corners (ix, ix+1) live at (h, h^1) -> one aligned float4
        const float4* tb4 = (const float4*)tb;
#pragma unroll
        for (int cc = 0; cc < 4; ++cc) {
            uint32_t h0 = (base[cc] ^ ux) & TMASK;
            float4 qv = tb4[h0 >> 1];
            bool hi = (h0 & 1u) != 0u;
            float2 e0 = hi ? make_float2(qv.z, qv.w) : make_float2(qv.x, qv.y);
            float2 e1 = hi ? make_float2(qv.x, qv.y) : make_float2(qv.z, qv.w);
            v[(cc << 1)]     = e0;
            v[(cc << 1) | 1] = e1;
        }
    } else {
        uint32_t h[8];
#pragma unroll
        for (int c = 0; c < 8; ++c)
            h[c] = (base[c >> 1] ^ (ux + (uint32_t)(c & 1))) & TMASK;
#pragma unroll
        for (int c = 0; c < 8; ++c) v[c] = tb[h[c]];
    }

    float f0 = 0.f, f1 = 0.f;
#pragma unroll
    for (int c = 0; c < 8; ++c) {
        float w = ((c & 1)        ? frx : 1.f - frx)
                * (((c >> 1) & 1) ? fry : 1.f - fry)
                * (((c >> 2) & 1) ? frz : 1.f - frz);
        f0 += w * v[c].x;
        f1 += w * v[c].y;
    }
    feats[oidx] = pack2(f0, f1);
}

// ---------------------------------------------------------------------------
// MFMA layout helpers (verified gfx950):
//   A-frag: A[m][k], m = lane&15, k = (lane>>4)*8 + j
//   B-frag: B[k][n], n = lane&15, k = (lane>>4)*8 + j
//   C/D:    D[row][col], col = lane&15, row = (lane>>4)*4 + reg
// C->B transpose via gfx950 permlane swaps (VALU, no DS on the spine).
// ---------------------------------------------------------------------------
__device__ __forceinline__ void quad_gather(uint32_t x, uint32_t& e02, uint32_t& e13)
{
    uint32_t u = x, v = x;
    asm("v_permlane32_swap_b32 %0, %1" : "+v"(u), "+v"(v));
    asm("v_permlane16_swap_b32 %0, %1" : "+v"(u), "+v"(v));
    e02 = u; e13 = v;
}

__device__ __forceinline__ bf16x8 trans_frag(uint32_t p01a, uint32_t p23a,
                                             uint32_t p01b, uint32_t p23b, bool hi)
{
    uint32_t a02, a13, c02, c13, b02, b13, e02, e13;
    quad_gather(p01a, a02, a13);
    quad_gather(p23a, c02, c13);
    quad_gather(p01b, b02, b13);
    quad_gather(p23b, e02, e13);
    union { bf16x8 v; uint32_t d[4]; } u;
    u.d[0] = hi ? b02 : a02;
    u.d[1] = hi ? e02 : c02;
    u.d[2] = hi ? b13 : a13;
    u.d[3] = hi ? e13 : c13;
    return u.v;
}

// a==b case (log_sigma rows): no selects needed.
__device__ __forceinline__ bf16x8 trans_frag1(uint32_t p01, uint32_t p23)
{
    uint32_t a02, a13, c02, c13;
    quad_gather(p01, a02, a13);
    quad_gather(p23, c02, c13);
    union { bf16x8 v; uint32_t d[4]; } u;
    u.d[0] = a02;
    u.d[1] = c02;
    u.d[2] = a13;
    u.d[3] = c13;
    return u.v;
}

// ---------------------------------------------------------------------------
// Kernel 2: MLP stack on matrix cores. r2/r3 best-measured variant
// (<=64.4us bound), with a DIAGNOSTIC 2x duplicated grid: blocks
// 3072..6143 redo the identical work (bit-identical racing writes are
// benign). Purpose: push k_mlp's duration above k_encode's so it finally
// appears in the top-5 counter table with VGPR_Count / Occupancy /
// VALUBusy / FETCH_SIZE — every theory so far (DS-chain, launch overhead,
// spills) died for lack of these numbers. Revert to 3072 next round.
// ---------------------------------------------------------------------------
__global__ __launch_bounds__(256, 4) void k_mlp(const uint32_t* __restrict__ feats,
                                                const uint4* __restrict__ wfrags,
                                                const float* __restrict__ x,
                                                const uint32_t* __restrict__ dirs,
                                                const float* __restrict__ db1,
                                                const float* __restrict__ db2,
                                                const float* __restrict__ cb2,
                                                const float* __restrict__ cb3,
                                                float* __restrict__ out)
{
    __shared__ uint4 wlds[24 * 64];   // 24576 B
#pragma unroll
    for (int t = 0; t < 6; ++t)
        wlds[t * 256 + threadIdx.x] = wfrags[t * 256 + threadIdx.x];

    int lane = threadIdx.x & 63;
    int q = lane >> 4, col = lane & 15;
    bool hi = q >= 2;
    int bwork = (blockIdx.x >= MLP_WORK_BLOCKS) ? blockIdx.x - MLP_WORK_BLOCKS
                                                : blockIdx.x;   // x2 duplication
    int wgid = bwork * 4 + (threadIdx.x >> 6);

    // ---- hoisted biases (loop-invariant) ----
    float4 b1v[4], c2v[4];
#pragma unroll
    for (int mt = 0; mt < 4; ++mt) {
        b1v[mt] = *(const float4*)&db1[mt * 16 + q * 4];
        c2v[mt] = *(const float4*)&cb2[mt * 16 + q * 4];
    }
    float4 b2v = *(const float4*)&db2[q * 4];
    float cb30 = cb3[0], cb31 = cb3[1], cb32 = cb3[2];

    __syncthreads();

#define LDW(f) ({ union { uint4 u_; bf16x8 v_; } w_; w_.u_ = wlds[(f) * 64 + lane]; w_.v_; })

#pragma unroll
    for (int it = 0; it < 2; ++it) {
        int g = (wgid * 2 + it) << 4;        // point base of this 16-group
        int pt = g + col;
        size_t pt3 = (size_t)pt * 3;

        // ---- B-frag of feats: pair index k/2 = q*4+w
        union { bf16x8 v; uint32_t d[4]; } Bf;
#pragma unroll
        for (int w = 0; w < 4; ++w)
            Bf.d[w] = feats[(size_t)(q * 4 + w) * NPTS + g + col];

        // ---- branchless early dir-PE loads (selected into frags later)
        uint32_t da[4], dbv[4];
#pragma unroll
        for (int j = 0; j < 4; ++j) {
            int pa = ((q - 2) * 4 + j) & 7;          // valid for q>=2
            da[j] = dirs[(size_t)pa * NPTS + pt];
            int pb = 8 + q * 4 + j;                  // valid q=0 (8..11), q=1 j<2 (12,13)
            pb = (pb > 13) ? 13 : pb;
            dbv[j] = dirs[(size_t)pb * NPTS + pt];
        }

        // ---- L1: feats(32) -> h1(64), bias, relu
        f32x4 T[4];
#pragma unroll
        for (int mt = 0; mt < 4; ++mt) {
            f32x4 c; c[0] = b1v[mt].x; c[1] = b1v[mt].y; c[2] = b1v[mt].z; c[3] = b1v[mt].w;
            T[mt] = MFMA_BF16(LDW(mt), Bf.v, c, 0, 0, 0);
        }
        uint32_t p01[4], p23[4];
#pragma unroll
        for (int mt = 0; mt < 4; ++mt) {
            p01[mt] = pack2t(fmaxf(T[mt][0], 0.f), fmaxf(T[mt][1], 0.f));
            p23[mt] = pack2t(fmaxf(T[mt][2], 0.f), fmaxf(T[mt][3], 0.f));
        }
        bf16x8 Bh0 = trans_frag(p01[0], p23[0], p01[1], p23[1], hi);
        bf16x8 Bh1 = trans_frag(p01[2], p23[2], p01[3], p23[3], hi);

        // ---- L2: h1(64) -> log_sigma(16), bias, linear
        f32x4 Dls;
        {
            f32x4 c; c[0] = b2v.x; c[1] = b2v.y; c[2] = b2v.z; c[3] = b2v.w;
            Dls = MFMA_BF16(LDW(4), Bh0, c, 0, 0, 0);
            Dls = MFMA_BF16(LDW(5), Bh1, Dls, 0, 0, 0);
        }
        uint32_t lp01 = pack2t(Dls[0], Dls[1]);
        uint32_t lp23 = pack2t(Dls[2], Dls[3]);

        // ---- av B-frags: rows 0..15 = ls (permlane transpose), 16..43 = dirs
        union { bf16x8 v; uint32_t d[4]; } Ba0, Ba1;
        Ba0.v = trans_frag1(lp01, lp23);               // valid for q<2
#pragma unroll
        for (int j = 0; j < 4; ++j) {
            Ba0.d[j] = (q >= 2) ? da[j] : Ba0.d[j];    // rows 16..31
            bool vld = (q == 0) | ((q == 1) & (j < 2));  // rows 32..43
            Ba1.d[j] = vld ? dbv[j] : 0u;
        }

        // ---- L3: av(43+1) -> c1(64), bias folded via row 43, relu
        f32x4 C1[4];
#pragma unroll
        for (int mt = 0; mt < 4; ++mt) {
            f32x4 c = {0.f, 0.f, 0.f, 0.f};
            c = MFMA_BF16(LDW(6 + 2 * mt), Ba0.v, c, 0, 0, 0);
            C1[mt] = MFMA_BF16(LDW(7 + 2 * mt), Ba1.v, c, 0, 0, 0);
        }
#pragma unroll
        for (int mt = 0; mt < 4; ++mt) {
            p01[mt] = pack2t(fmaxf(C1[mt][0], 0.f), fmaxf(C1[mt][1], 0.f));
            p23[mt] = pack2t(fmaxf(C1[mt][2], 0.f), fmaxf(C1[mt][3], 0.f));
        }
        bf16x8 Bc0 = trans_frag(p01[0], p23[0], p01[1], p23[1], hi);
        bf16x8 Bc1 = trans_frag(p01[2], p23[2], p01[3], p23[3], hi);

        // ---- L4: c1(64) -> c2(64), bias, relu
        f32x4 C2[4];
#pragma unroll
        for (int mt = 0; mt < 4; ++mt) {
            f32x4 c; c[0] = c2v[mt].x; c[1] = c2v[mt].y; c[2] = c2v[mt].z; c[3] = c2v[mt].w;
            c = MFMA_BF16(LDW(14 + 2 * mt), Bc0, c, 0, 0, 0);
            C2[mt] = MFMA_BF16(LDW(15 + 2 * mt), Bc1, c, 0, 0, 0);
        }
#pragma unroll
        for (int mt = 0; mt < 4; ++mt) {
            p01[mt] = pack2t(fmaxf(C2[mt][0], 0.f), fmaxf(C2[mt][1], 0.f));
            p23[mt] = pack2t(fmaxf(C2[mt][2], 0.f), fmaxf(C2[mt][3], 0.f));
        }
        bf16x8 Bd0 = trans_frag(p01[0], p23[0], p01[1], p23[1], hi);
        bf16x8 Bd1 = trans_frag(p01[2], p23[2], p01[3], p23[3], hi);

        // ---- L5: c2(64) -> color(3), bias, sigmoid
        f32x4 c5 = {0.f, 0.f, 0.f, 0.f};
        if (q == 0) { c5[0] = cb30; c5[1] = cb31; c5[2] = cb32; }
        f32x4 Dc = MFMA_BF16(LDW(22), Bd0, c5, 0, 0, 0);
        Dc = MFMA_BF16(LDW(23), Bd1, Dc, 0, 0, 0);

        // ---- outputs
        if (q == 0) {
            float xfx = x[pt3 + 0] + 0.5f;
            float xfy = x[pt3 + 1] + 0.5f;
            float xfz = x[pt3 + 2] + 0.5f;
            bool m = (xfx > 0.f) && (xfx < 1.f) && (xfy > 0.f) && (xfy < 1.f) &&
                     (xfz > 0.f) && (xfz < 1.f);
            out[pt3 + 0] = m ? 1.f / (1.f + __expf(-Dc[0])) : 0.f;
            out[pt3 + 1] = m ? 1.f / (1.f + __expf(-Dc[1])) : 0.f;
            out[pt3 + 2] = m ? 1.f / (1.f + __expf(-Dc[2])) : 0.f;
            out[(size_t)3 * NPTS + pt] = m ? __expf(Dls[0]) : 0.f;
        }
    }
#undef LDW
}

extern "C" void kernel_launch(void* const* d_in, const int* in_sizes, int n_in,
                              void* d_out, int out_size, void* d_ws, size_t ws_size,
                              hipStream_t stream) {
    const float* x      = (const float*)d_in[0];
    const float* rdir   = (const float*)d_in[1];
    const float* tables = (const float*)d_in[2];
    const float* dW1 = (const float*)d_in[3];
    const float* db1 = (const float*)d_in[4];
    const float* dW2 = (const float*)d_in[5];
    const float* db2 = (const float*)d_in[6];
    const float* cW1 = (const float*)d_in[7];
    const float* cb1 = (const float*)d_in[8];
    const float* cW2 = (const float*)d_in[9];
    const float* cb2 = (const float*)d_in[10];
    const float* cW3 = (const float*)d_in[11];
    const float* cb3 = (const float*)d_in[12];
    float* out = (float*)d_out;

    uint4*    wfrags = (uint4*)d_ws;                         // 24 KB
    uint32_t* feats  = (uint32_t*)((char*)d_ws + 32768);     // 16*NPTS*4 B
    uint32_t* dirs   = (uint32_t*)((char*)d_ws + 32768 + (size_t)16 * NPTS * 4); // 14*NPTS*4 B

    k_encode<<<ENC_BLOCKS + PREP_BLOCKS + PE_BLOCKS, 256, 0, stream>>>(
        x, tables, feats, dW1, dW2, cW1, cb1, cW2, cW3, wfrags, rdir, dirs);
    k_mlp<<<MLP_BLOCKS, 256, 0, stream>>>(feats, wfrags, x, dirs,
                                          db1, db2, cb2, cb3, out);
}

// Round 7
// 239.972 us; speedup vs baseline: 1.0849x; 1.0849x over previous
//
#include <hip/hip_runtime.h>
#include <hip/hip_bf16.h>
#include <cstdint>

#define NPTS (2048 * 192)          // 393216 points
#define TBL  (1u << 19)            // hash table size per level
#define TMASK (TBL - 1u)
#define PBLOCKS (NPTS / 256)       // 1536 blocks per level
#define ENC_BLOCKS (PBLOCKS * 16)  // 24576
#define PREP_BLOCKS 6              // 24 frags * 64 lanes / 256
#define PE_BLOCKS PBLOCKS          // 1536 dir-PE precompute blocks
#define MLP_BLOCKS 3072            // 3072 blocks * 4 waves * 2 groups * 16 pts
#define P2 2654435761u
#define P3 805459861u

// geomspace(16, 2048, 16).astype(int)
__constant__ float LVLS[16] = {16.f, 22.f, 30.f, 42.f, 58.f, 80.f, 111.f, 153.f,
                               212.f, 294.f, 406.f, 561.f, 776.f, 1072.f, 1482.f, 2048.f};

__device__ __forceinline__ uint32_t f2bf(float f) {
    uint32_t u = __float_as_uint(f);
    return (u + 0x7FFFu + ((u >> 16) & 1u)) >> 16;   // RNE bf16 (weights/feats)
}
__device__ __forceinline__ uint32_t pack2(float a, float b) {
    return f2bf(a) | (f2bf(b) << 16);
}
// 1-instruction truncating bf16 pack: [a_hi16 | b_hi16 << 16] via v_perm_b32.
__device__ __forceinline__ uint32_t pack2t(float a, float b) {
    return __builtin_amdgcn_perm(__float_as_uint(b), __float_as_uint(a),
                                 0x07060302u);
}

#if __has_builtin(__builtin_amdgcn_sinf)
#define SIN_REV(x) __builtin_amdgcn_sinf(x)   // sin(2*pi*x)
#else
#define SIN_REV(x) __sinf(6.28318530717958647f * (x))
#endif

typedef __attribute__((ext_vector_type(8))) short bf16x8;   // MFMA A/B frag
typedef __attribute__((ext_vector_type(4))) float f32x4;    // MFMA C/D frag

#define MFMA_BF16 __builtin_amdgcn_mfma_f32_16x16x32_bf16

// av-vector row value for rows 16..63. ONE transcendental per row:
// cos(x) = sin(x + 0.25 rev). Evaluated once per point in the k_encode PE pass.
__device__ __forceinline__ float pe_val(int r, float rx, float ry, float rz)
{
    int t = r - 19;
    int d = t >> 3;
    int s = t & 7;
    float comp = (d == 0) ? rx : ((d == 1) ? ry : rz);
    float a = ldexpf(comp, s & 3) + ((s >= 4) ? 0.25f : 0.0f);
    float v = SIN_REV(a);
    if (r == 16) v = rx;
    if (r == 17) v = ry;
    if (r == 18) v = rz;
    if (r == 43) v = 1.0f;
    if (r > 43)  v = 0.0f;
    return v;
}

// ---------------------------------------------------------------------------
// Kernel 1: dir-PE planes + weight prepack + hash-grid encode.
// Round-13 ledger (from the r6 2x-grid diagnostic): k_mlp ~= 16-19us,
// harness fixed cost ~= 104us (17 dispatches/iter), so enc (~119.5us) is
// the only remaining lever. It sits ~10% over the ~105-108us L2-request
// floor (32M merged reqs / 128 ch / 2.4GHz). Two tail-trim edits:
//   * PE/prep blocks now come FIRST in the grid — they previously launched
//     after all 24576 encode blocks and extended the drain; now their work
//     folds into the ramp. XCD-affine level mapping unaffected (constant
//     slot rotation).
//   * masked points skip the feats store entirely (was feats=0): masked
//     feats are never consumed — k_mlp masks its outputs, and garbage in a
//     masked point's B-column cannot contaminate other MFMA columns.
//     ~25% fewer store requests.
// Gather hot path UNCHANGED (coalescer already merges coarse-level
// same-cell lanes; fine-level randomness is irreducible).
// ---------------------------------------------------------------------------
__global__ __launch_bounds__(256) void k_encode(const float* __restrict__ x,
                                                const float* __restrict__ tables,
                                                uint32_t* __restrict__ feats,
                                                const float* __restrict__ dW1,
                                                const float* __restrict__ dW2,
                                                const float* __restrict__ cW1,
                                                const float* __restrict__ cb1,
                                                const float* __restrict__ cW2,
                                                const float* __restrict__ cW3,
                                                uint4* __restrict__ wfrags,
                                                const float* __restrict__ rdir,
                                                uint32_t* __restrict__ dirs)
{
    if (blockIdx.x < PE_BLOCKS) {
        // ---- dir positional-encoding precompute (first 1536 blocks) ----
        int p = blockIdx.x * 256 + threadIdx.x;
        size_t p3 = (size_t)p * 3;
        float rx = rdir[p3 + 0], ry = rdir[p3 + 1], rz = rdir[p3 + 2];
#pragma unroll
        for (int i = 0; i < 14; ++i)
            dirs[(size_t)i * NPTS + p] =
                pack2t(pe_val(16 + 2 * i, rx, ry, rz),
                       pe_val(17 + 2 * i, rx, ry, rz));
        return;
    }
    if (blockIdx.x < PE_BLOCKS + PREP_BLOCKS) {
        // ---- weight prepack (6 blocks; consumed by k_mlp) ----
        int t = (blockIdx.x - PE_BLOCKS) * 256 + threadIdx.x;
        if (t >= 24 * 64) return;
        int frag = t >> 6, lane = t & 63;
        const float* W; const float* bfold = nullptr;
        int OUT, Kact, Mact, k0, m0;
        if (frag < 4)       { W = dW1; OUT = 64; Kact = 32; Mact = 64; k0 = 0;               m0 = frag * 16; }
        else if (frag < 6)  { W = dW2; OUT = 16; Kact = 64; Mact = 16; k0 = (frag - 4) * 32; m0 = 0; }
        else if (frag < 14) { int i = frag - 6;  W = cW1; OUT = 64; Kact = 43; Mact = 64;
                              k0 = (i & 1) * 32; m0 = (i >> 1) * 16; bfold = cb1; }
        else if (frag < 22) { int i = frag - 14; W = cW2; OUT = 64; Kact = 64; Mact = 64;
                              k0 = (i & 1) * 32; m0 = (i >> 1) * 16; }
        else                { W = cW3; OUT = 3;  Kact = 64; Mact = 3;  k0 = (frag - 22) * 32; m0 = 0; }
        int m  = m0 + (lane & 15);
        int kq = k0 + ((lane >> 4) << 3);
        uint32_t d[4];
#pragma unroll
        for (int j = 0; j < 4; ++j) {
            float a0 = 0.f, a1 = 0.f;
            int ka = kq + 2 * j, kb = ka + 1;
            if (m < Mact) {
                a0 = (ka < Kact) ? W[(size_t)ka * OUT + m]
                                 : ((bfold && ka == Kact) ? bfold[m] : 0.f);
                a1 = (kb < Kact) ? W[(size_t)kb * OUT + m]
                                 : ((bfold && kb == Kact) ? bfold[m] : 0.f);
            }
            d[j] = f2bf(a0) | (f2bf(a1) << 16);
        }
        wfrags[t] = make_uint4(d[0], d[1], d[2], d[3]);
        return;
    }

    // ---- XCD-affine decode of (level, point-block) ----
    int i    = blockIdx.x - (PE_BLOCKS + PREP_BLOCKS);  // 0..24575
    int xs   = i & 7;                   // XCD slot (constant rotation vs phys)
    int j    = i >> 3;                  // 0..3071
    int half = j / PBLOCKS;             // 0: levels 0-7, 1: levels 8-15
    int pb   = j - half * PBLOCKS;      // point-block 0..1535
    int lvl  = xs + (half << 3);
    int p    = pb * 256 + threadIdx.x;

    size_t p3 = (size_t)p * 3;
    float x0 = x[p3 + 0] + 0.5f;
    float x1 = x[p3 + 1] + 0.5f;
    float x2 = x[p3 + 2] + 0.5f;
    size_t oidx = (size_t)lvl * NPTS + p;

    bool m = (x0 > 0.f) && (x0 < 1.f) && (x1 > 0.f) && (x1 < 1.f) &&
             (x2 > 0.f) && (x2 < 1.f);
    if (!m) return;                     // masked: feats never consumed downstream

    float s  = LVLS[lvl];
    float px = x0 * s, py = x1 * s, pz = x2 * s;
    float flx = floorf(px), fly = floorf(py), flz = floorf(pz);
    float frx = px - flx,   fry = py - fly,   frz = pz - flz;
    int ix = (int)flx, iy = (int)fly, iz = (int)flz;
    uint32_t ux = (uint32_t)ix, uy = (uint32_t)iy, uz = (uint32_t)iz;

    uint32_t base[4];
    base[0] = (uy * P2) ^ (uz * P3);
    base[1] = ((uy + 1u) * P2) ^ (uz * P3);
    base[2] = (uy * P2) ^ ((uz + 1u) * P3);
    base[3] = ((uy + 1u) * P2) ^ ((uz + 1u) * P3);

    const float2* tb = (const float2*)tables + (size_t)lvl * TBL;

    float2 v[8];
    if ((ix & 1) == 0) {
        // even ix: corners (ix, ix+1) live at (h, h^1) -> one aligned float4
        const float4* tb4 = (const float4*)tb;
#pragma unroll
        for (int cc = 0; cc < 4; ++cc) {
            uint32_t h0 = (base[cc] ^ ux) & TMASK;
            float4 qv = tb4[h0 >> 1];
            bool hi = (h0 & 1u) != 0u;
            float2 e0 = hi ? make_float2(qv.z, qv.w) : make_float2(qv.x, qv.y);
            float2 e1 = hi ? make_float2(qv.x, qv.y) : make_float2(qv.z, qv.w);
            v[(cc << 1)]     = e0;
            v[(cc << 1) | 1] = e1;
        }
    } else {
        uint32_t h[8];
#pragma unroll
        for (int c = 0; c < 8; ++c)
            h[c] = (base[c >> 1] ^ (ux + (uint32_t)(c & 1))) & TMASK;
#pragma unroll
        for (int c = 0; c < 8; ++c) v[c] = tb[h[c]];
    }

    float f0 = 0.f, f1 = 0.f;
#pragma unroll
    for (int c = 0; c < 8; ++c) {
        float w = ((c & 1)        ? frx : 1.f - frx)
                * (((c >> 1) & 1) ? fry : 1.f - fry)
                * (((c >> 2) & 1) ? frz : 1.f - frz);
        f0 += w * v[c].x;
        f1 += w * v[c].y;
    }
    feats[oidx] = pack2(f0, f1);
}

// ---------------------------------------------------------------------------
// MFMA layout helpers (verified gfx950):
//   A-frag: A[m][k], m = lane&15, k = (lane>>4)*8 + j
//   B-frag: B[k][n], n = lane&15, k = (lane>>4)*8 + j
//   C/D:    D[row][col], col = lane&15, row = (lane>>4)*4 + reg
// C->B transpose via gfx950 permlane swaps (VALU, no DS on the spine).
// ---------------------------------------------------------------------------
__device__ __forceinline__ void quad_gather(uint32_t x, uint32_t& e02, uint32_t& e13)
{
    uint32_t u = x, v = x;
    asm("v_permlane32_swap_b32 %0, %1" : "+v"(u), "+v"(v));
    asm("v_permlane16_swap_b32 %0, %1" : "+v"(u), "+v"(v));
    e02 = u; e13 = v;
}

__device__ __forceinline__ bf16x8 trans_frag(uint32_t p01a, uint32_t p23a,
                                             uint32_t p01b, uint32_t p23b, bool hi)
{
    uint32_t a02, a13, c02, c13, b02, b13, e02, e13;
    quad_gather(p01a, a02, a13);
    quad_gather(p23a, c02, c13);
    quad_gather(p01b, b02, b13);
    quad_gather(p23b, e02, e13);
    union { bf16x8 v; uint32_t d[4]; } u;
    u.d[0] = hi ? b02 : a02;
    u.d[1] = hi ? e02 : c02;
    u.d[2] = hi ? b13 : a13;
    u.d[3] = hi ? e13 : c13;
    return u.v;
}

// a==b case (log_sigma rows): no selects needed.
__device__ __forceinline__ bf16x8 trans_frag1(uint32_t p01, uint32_t p23)
{
    uint32_t a02, a13, c02, c13;
    quad_gather(p01, a02, a13);
    quad_gather(p23, c02, c13);
    union { bf16x8 v; uint32_t d[4]; } u;
    u.d[0] = a02;
    u.d[1] = c02;
    u.d[2] = a13;
    u.d[3] = c13;
    return u.v;
}

// ---------------------------------------------------------------------------
// Kernel 2: MLP stack on matrix cores. Best-measured variant, grid back to
// 3072 (r6 diagnostic duplication removed). Measured ~16-19us by marginal
// cost — no longer an optimization target.
// ---------------------------------------------------------------------------
__global__ __launch_bounds__(256, 4) void k_mlp(const uint32_t* __restrict__ feats,
                                                const uint4* __restrict__ wfrags,
                                                const float* __restrict__ x,
                                                const uint32_t* __restrict__ dirs,
                                                const float* __restrict__ db1,
                                                const float* __restrict__ db2,
                                                const float* __restrict__ cb2,
                                                const float* __restrict__ cb3,
                                                float* __restrict__ out)
{
    __shared__ uint4 wlds[24 * 64];   // 24576 B
#pragma unroll
    for (int t = 0; t < 6; ++t)
        wlds[t * 256 + threadIdx.x] = wfrags[t * 256 + threadIdx.x];

    int lane = threadIdx.x & 63;
    int q = lane >> 4, col = lane & 15;
    bool hi = q >= 2;
    int wgid = blockIdx.x * 4 + (threadIdx.x >> 6);

    // ---- hoisted biases (loop-invariant) ----
    float4 b1v[4], c2v[4];
#pragma unroll
    for (int mt = 0; mt < 4; ++mt) {
        b1v[mt] = *(const float4*)&db1[mt * 16 + q * 4];
        c2v[mt] = *(const float4*)&cb2[mt * 16 + q * 4];
    }
    float4 b2v = *(const float4*)&db2[q * 4];
    float cb30 = cb3[0], cb31 = cb3[1], cb32 = cb3[2];

    __syncthreads();

#define LDW(f) ({ union { uint4 u_; bf16x8 v_; } w_; w_.u_ = wlds[(f) * 64 + lane]; w_.v_; })

#pragma unroll
    for (int it = 0; it < 2; ++it) {
        int g = (wgid * 2 + it) << 4;        // point base of this 16-group
        int pt = g + col;
        size_t pt3 = (size_t)pt * 3;

        // ---- B-frag of feats: pair index k/2 = q*4+w
        union { bf16x8 v; uint32_t d[4]; } Bf;
#pragma unroll
        for (int w = 0; w < 4; ++w)
            Bf.d[w] = feats[(size_t)(q * 4 + w) * NPTS + g + col];

        // ---- branchless early dir-PE loads (selected into frags later)
        uint32_t da[4], dbv[4];
#pragma unroll
        for (int j = 0; j < 4; ++j) {
            int pa = ((q - 2) * 4 + j) & 7;          // valid for q>=2
            da[j] = dirs[(size_t)pa * NPTS + pt];
            int pb = 8 + q * 4 + j;                  // valid q=0 (8..11), q=1 j<2 (12,13)
            pb = (pb > 13) ? 13 : pb;
            dbv[j] = dirs[(size_t)pb * NPTS + pt];
        }

        // ---- L1: feats(32) -> h1(64), bias, relu
        f32x4 T[4];
#pragma unroll
        for (int mt = 0; mt < 4; ++mt) {
            f32x4 c; c[0] = b1v[mt].x; c[1] = b1v[mt].y; c[2] = b1v[mt].z; c[3] = b1v[mt].w;
            T[mt] = MFMA_BF16(LDW(mt), Bf.v, c, 0, 0, 0);
        }
        uint32_t p01[4], p23[4];
#pragma unroll
        for (int mt = 0; mt < 4; ++mt) {
            p01[mt] = pack2t(fmaxf(T[mt][0], 0.f), fmaxf(T[mt][1], 0.f));
            p23[mt] = pack2t(fmaxf(T[mt][2], 0.f), fmaxf(T[mt][3], 0.f));
        }
        bf16x8 Bh0 = trans_frag(p01[0], p23[0], p01[1], p23[1], hi);
        bf16x8 Bh1 = trans_frag(p01[2], p23[2], p01[3], p23[3], hi);

        // ---- L2: h1(64) -> log_sigma(16), bias, linear
        f32x4 Dls;
        {
            f32x4 c; c[0] = b2v.x; c[1] = b2v.y; c[2] = b2v.z; c[3] = b2v.w;
            Dls = MFMA_BF16(LDW(4), Bh0, c, 0, 0, 0);
            Dls = MFMA_BF16(LDW(5), Bh1, Dls, 0, 0, 0);
        }
        uint32_t lp01 = pack2t(Dls[0], Dls[1]);
        uint32_t lp23 = pack2t(Dls[2], Dls[3]);

        // ---- av B-frags: rows 0..15 = ls (permlane transpose), 16..43 = dirs
        union { bf16x8 v; uint32_t d[4]; } Ba0, Ba1;
        Ba0.v = trans_frag1(lp01, lp23);               // valid for q<2
#pragma unroll
        for (int j = 0; j < 4; ++j) {
            Ba0.d[j] = (q >= 2) ? da[j] : Ba0.d[j];    // rows 16..31
            bool vld = (q == 0) | ((q == 1) & (j < 2));  // rows 32..43
            Ba1.d[j] = vld ? dbv[j] : 0u;
        }

        // ---- L3: av(43+1) -> c1(64), bias folded via row 43, relu
        f32x4 C1[4];
#pragma unroll
        for (int mt = 0; mt < 4; ++mt) {
            f32x4 c = {0.f, 0.f, 0.f, 0.f};
            c = MFMA_BF16(LDW(6 + 2 * mt), Ba0.v, c, 0, 0, 0);
            C1[mt] = MFMA_BF16(LDW(7 + 2 * mt), Ba1.v, c, 0, 0, 0);
        }
#pragma unroll
        for (int mt = 0; mt < 4; ++mt) {
            p01[mt] = pack2t(fmaxf(C1[mt][0], 0.f), fmaxf(C1[mt][1], 0.f));
            p23[mt] = pack2t(fmaxf(C1[mt][2], 0.f), fmaxf(C1[mt][3], 0.f));
        }
        bf16x8 Bc0 = trans_frag(p01[0], p23[0], p01[1], p23[1], hi);
        bf16x8 Bc1 = trans_frag(p01[2], p23[2], p01[3], p23[3], hi);

        // ---- L4: c1(64) -> c2(64), bias, relu
        f32x4 C2[4];
#pragma unroll
        for (int mt = 0; mt < 4; ++mt) {
            f32x4 c; c[0] = c2v[mt].x; c[1] = c2v[mt].y; c[2] = c2v[mt].z; c[3] = c2v[mt].w;
            c = MFMA_BF16(LDW(14 + 2 * mt), Bc0, c, 0, 0, 0);
            C2[mt] = MFMA_BF16(LDW(15 + 2 * mt), Bc1, c, 0, 0, 0);
        }
#pragma unroll
        for (int mt = 0; mt < 4; ++mt) {
            p01[mt] = pack2t(fmaxf(C2[mt][0], 0.f), fmaxf(C2[mt][1], 0.f));
            p23[mt] = pack2t(fmaxf(C2[mt][2], 0.f), fmaxf(C2[mt][3], 0.f));
        }
        bf16x8 Bd0 = trans_frag(p01[0], p23[0], p01[1], p23[1], hi);
        bf16x8 Bd1 = trans_frag(p01[2], p23[2], p01[3], p23[3], hi);

        // ---- L5: c2(64) -> color(3), bias, sigmoid
        f32x4 c5 = {0.f, 0.f, 0.f, 0.f};
        if (q == 0) { c5[0] = cb30; c5[1] = cb31; c5[2] = cb32; }
        f32x4 Dc = MFMA_BF16(LDW(22), Bd0, c5, 0, 0, 0);
        Dc = MFMA_BF16(LDW(23), Bd1, Dc, 0, 0, 0);

        // ---- outputs
        if (q == 0) {
            float xfx = x[pt3 + 0] + 0.5f;
            float xfy = x[pt3 + 1] + 0.5f;
            float xfz = x[pt3 + 2] + 0.5f;
            bool m = (xfx > 0.f) && (xfx < 1.f) && (xfy > 0.f) && (xfy < 1.f) &&
                     (xfz > 0.f) && (xfz < 1.f);
            out[pt3 + 0] = m ? 1.f / (1.f + __expf(-Dc[0])) : 0.f;
            out[pt3 + 1] = m ? 1.f / (1.f + __expf(-Dc[1])) : 0.f;
            out[pt3 + 2] = m ? 1.f / (1.f + __expf(-Dc[2])) : 0.f;
            out[(size_t)3 * NPTS + pt] = m ? __expf(Dls[0]) : 0.f;
        }
    }
#undef LDW
}

extern "C" void kernel_launch(void* const* d_in, const int* in_sizes, int n_in,
                              void* d_out, int out_size, void* d_ws, size_t ws_size,
                              hipStream_t stream) {
    const float* x      = (const float*)d_in[0];
    const float* rdir   = (const float*)d_in[1];
    const float* tables = (const float*)d_in[2];
    const float* dW1 = (const float*)d_in[3];
    const float* db1 = (const float*)d_in[4];
    const float* dW2 = (const float*)d_in[5];
    const float* db2 = (const float*)d_in[6];
    const float* cW1 = (const float*)d_in[7];
    const float* cb1 = (const float*)d_in[8];
    const float* cW2 = (const float*)d_in[9];
    const float* cb2 = (const float*)d_in[10];
    const float* cW3 = (const float*)d_in[11];
    const float* cb3 = (const float*)d_in[12];
    float* out = (float*)d_out;

    uint4*    wfrags = (uint4*)d_ws;                         // 24 KB
    uint32_t* feats  = (uint32_t*)((char*)d_ws + 32768);     // 16*NPTS*4 B
    uint32_t* dirs   = (uint32_t*)((char*)d_ws + 32768 + (size_t)16 * NPTS * 4); // 14*NPTS*4 B

    k_encode<<<PE_BLOCKS + PREP_BLOCKS + ENC_BLOCKS, 256, 0, stream>>>(
        x, tables, feats, dW1, dW2, cW1, cb1, cW2, cW3, wfrags, rdir, dirs);
    k_mlp<<<MLP_BLOCKS, 256, 0, stream>>>(feats, wfrags, x, dirs,
                                          db1, db2, cb2, cb3, out);
}